// Round 8
// baseline (475.989 us; speedup 1.0000x reference)
//
#include <hip/hip_runtime.h>

typedef __bf16 bf16;
typedef __attribute__((ext_vector_type(8))) __bf16 bf16x8;
typedef __attribute__((ext_vector_type(4))) __bf16 bf16x4;
typedef __attribute__((ext_vector_type(2))) __bf16 bf16x2;
typedef __attribute__((ext_vector_type(4))) float f32x4;
typedef __attribute__((ext_vector_type(4))) float fvec4;

#define NB 2
#define SEQ 2048
#define DM 1024
#define NH 8
#define HD 128

// ---------------------------------------------------------------------------
// Mask: detect encoding, pack to 1 bit/elem. (proven)
// ---------------------------------------------------------------------------
__global__ void mask_detect(const unsigned int* __restrict__ m,
                            unsigned int* __restrict__ flag)
{
    __shared__ unsigned int s[256];
    unsigned int f = 0;
    for (int i = threadIdx.x; i < 1024; i += 256) {
        const unsigned int w = m[i];
        if ((w & 0xFEFEFEFEu) == 0u && (w & 0xFFFFFF00u) != 0u) f = 1;
    }
    s[threadIdx.x] = f;
    __syncthreads();
    if (threadIdx.x == 0) {
        unsigned int r = 0;
        for (int i = 0; i < 256; i++) r |= s[i];
        *flag = r;
    }
}

__global__ __launch_bounds__(256) void mask_pack(
    const void* __restrict__ m, const unsigned int* __restrict__ flag,
    unsigned long long* __restrict__ bits)
{
    const int gid = blockIdx.x * 256 + threadIdx.x;
    bool mk;
    if (*flag & 1u)
        mk = ((const unsigned char*)m)[gid] != 0;
    else
        mk = ((const unsigned int*)m)[gid] != 0u;
    const unsigned long long b = __ballot(mk);
    if ((threadIdx.x & 63) == 0) bits[gid >> 6] = b;
}

// ---------------------------------------------------------------------------
// W transpose+convert (proven round 7).
// ---------------------------------------------------------------------------
__global__ __launch_bounds__(256) void transw_kernel(
    const float* __restrict__ Wq, const float* __restrict__ Wk,
    const float* __restrict__ Wv,
    bf16* __restrict__ Wtq, bf16* __restrict__ Wtk, bf16* __restrict__ Wtv)
{
    __shared__ float T[64 * 65];
    const int z = blockIdx.z;
    const float* W = (z == 0) ? Wq : (z == 1) ? Wk : Wv;
    bf16* Wt = (z == 0) ? Wtq : (z == 1) ? Wtk : Wtv;

    const int tid = threadIdx.x;
    const int k0 = blockIdx.y * 64;
    const int n0 = blockIdx.x * 64;

    #pragma unroll
    for (int i = 0; i < 16; i++) {
        const int gidx = i * 256 + tid;
        const int kk = gidx >> 6, nn = gidx & 63;
        T[kk * 65 + nn] = W[(size_t)(k0 + kk) * DM + n0 + nn];
    }
    __syncthreads();
    #pragma unroll
    for (int i = 0; i < 8; i++) {
        const int p  = i * 256 + tid;
        const int nn = p >> 5;
        const int kp = (p & 31) * 2;
        bf16x2 v;
        v.x = (bf16)T[kp * 65 + nn];
        v.y = (bf16)T[(kp + 1) * 65 + nn];
        *(bf16x2*)(Wt + (size_t)(n0 + nn) * DM + k0 + kp) = v;
    }
}

// ---------------------------------------------------------------------------
// Projection GEMM (proven round 7): Wt bf16, BK=64, XOR-swizzle LDS.
// ---------------------------------------------------------------------------
__global__ __launch_bounds__(256) void proj_kernel(
    const float* __restrict__ qi, const float* __restrict__ ki,
    const float* __restrict__ vi,
    const bf16* __restrict__ Wtq, const bf16* __restrict__ Wtk,
    const bf16* __restrict__ Wtv,
    const float* __restrict__ bq, const float* __restrict__ bk,
    const float* __restrict__ bv,
    bf16* __restrict__ Qo, bf16* __restrict__ Ko, bf16* __restrict__ Vto)
{
    __shared__ __align__(16) bf16 As[128 * 64];
    __shared__ __align__(16) bf16 Bs[128 * 64];

    const int pz = blockIdx.z;
    const float* X = (pz == 0) ? qi : (pz == 1) ? ki : vi;
    const bf16* Wt = (pz == 0) ? Wtq : (pz == 1) ? Wtk : Wtv;
    const float* bias = (pz == 0) ? bq : (pz == 1) ? bk : bv;
    bf16* dst = (pz == 0) ? Qo : (pz == 1) ? Ko : Vto;

    const int tid  = threadIdx.x;
    const int lane = tid & 63;
    const int w    = tid >> 6;
    const int q16  = lane >> 4;
    const int l15  = lane & 15;

    const int m0 = blockIdx.y * 128;
    const int n0 = blockIdx.x * 128;
    const int wm = (w >> 1) * 64;
    const int wn = (w & 1) * 64;

    f32x4 acc[4][4] = {};

    for (int k0 = 0; k0 < DM; k0 += 64) {
        __syncthreads();
        #pragma unroll
        for (int i = 0; i < 8; i++) {
            const int gidx = i * 256 + tid;
            const int row = gidx >> 4;
            const int c4  = gidx & 15;
            const fvec4 xv =
                *(const fvec4*)(X + (size_t)(m0 + row) * DM + k0 + c4 * 4);
            bf16x4 hv;
            hv.x = (bf16)xv.x; hv.y = (bf16)xv.y;
            hv.z = (bf16)xv.z; hv.w = (bf16)xv.w;
            const int seg  = c4 >> 1, half = c4 & 1;
            *(bf16x4*)(As + row * 64 + ((seg ^ (row & 7)) << 3) + half * 4) = hv;
        }
        #pragma unroll
        for (int i = 0; i < 4; i++) {
            const int gidx = i * 256 + tid;
            const int row = gidx >> 3;
            const int seg = gidx & 7;
            *(bf16x8*)(Bs + row * 64 + ((seg ^ (row & 7)) << 3)) =
                *(const bf16x8*)(Wt + (size_t)(n0 + row) * DM + k0 + seg * 8);
        }
        __syncthreads();

        #pragma unroll
        for (int c = 0; c < 2; c++) {
            bf16x8 af[4], bfr[4];
            #pragma unroll
            for (int mi = 0; mi < 4; mi++) {
                const int row = wm + mi * 16 + l15;
                const int sg = (c * 4 + q16) ^ (row & 7);
                af[mi] = *(const bf16x8*)(As + row * 64 + sg * 8);
            }
            #pragma unroll
            for (int ni = 0; ni < 4; ni++) {
                const int row = wn + ni * 16 + l15;
                const int sg = (c * 4 + q16) ^ (row & 7);
                bfr[ni] = *(const bf16x8*)(Bs + row * 64 + sg * 8);
            }
            #pragma unroll
            for (int mi = 0; mi < 4; mi++)
                #pragma unroll
                for (int ni = 0; ni < 4; ni++)
                    acc[mi][ni] = __builtin_amdgcn_mfma_f32_16x16x32_bf16(
                        af[mi], bfr[ni], acc[mi][ni], 0, 0, 0);
        }
    }

    float bias_v[4];
    #pragma unroll
    for (int ni = 0; ni < 4; ni++)
        bias_v[ni] = bias[n0 + wn + ni * 16 + l15];

    #pragma unroll
    for (int mi = 0; mi < 4; mi++) {
        #pragma unroll
        for (int ni = 0; ni < 4; ni++) {
            const int n  = n0 + wn + ni * 16 + l15;
            const int h  = n >> 7;
            const int hd = n & (HD - 1);
            #pragma unroll
            for (int r = 0; r < 4; r++) {
                const int m = m0 + wm + mi * 16 + q16 * 4 + r;
                const int b = m >> 11;
                const int s = m & (SEQ - 1);
                const float val = acc[mi][ni][r] + bias_v[ni];
                size_t idx;
                if (pz == 2)
                    idx = ((size_t)(b * NH + h) * HD + hd) * SEQ + s;
                else
                    idx = ((size_t)(b * NH + h) * SEQ + s) * HD + hd;
                dst[idx] = (bf16)val;
            }
        }
    }
}

// ---------------------------------------------------------------------------
// Flash attention, split-K (round-5 structure + THE FIX): each wave's l_i is
// a per-lane partial (each lane holds only 4 of the row's 64 probabilities
// per iteration). It must be shuffle-reduced across the quad's 16 lanes
// BEFORE publishing to the merge -- round 5/6 published lane0's 1/16 partial,
// inflating the output ~16x (absmax 6.19). m_i needs no fix (max-reduced
// every iteration); partial-O needs no fix (each (row,d) lives in one lane).
// ---------------------------------------------------------------------------
__global__ __launch_bounds__(256, 4) void attn_kernel(
    const bf16* __restrict__ Q, const bf16* __restrict__ K,
    const bf16* __restrict__ Vt, const unsigned long long* __restrict__ mb64,
    float* __restrict__ out)
{
    __shared__ float Buf[4 * 2112];      // per wave: Ps (bf16 16x72) then Om
    __shared__ float Mm[4][16], Ll[4][16];

    const int tid  = threadIdx.x;
    const int lane = tid & 63;
    const int w    = tid >> 6;
    const int q16  = lane >> 4;
    const int l15  = lane & 15;

    const int b  = blockIdx.z;
    const int h  = blockIdx.y;
    const int q0 = blockIdx.x * 16;
    const int bh = b * NH + h;

    const bf16* Qb = Q  + (size_t)bh * SEQ * HD;
    const bf16* Kb = K  + (size_t)bh * SEQ * HD;
    const bf16* Vb = Vt + (size_t)bh * HD * SEQ;
    const unsigned long long* mbq = mb64 + (size_t)b * (SEQ * SEQ / 64);

    bf16x8 qf[4];
    #pragma unroll
    for (int c = 0; c < 4; c++)
        qf[c] = *(const bf16x8*)(Qb + (size_t)(q0 + l15) * HD + c * 32 + q16 * 8);

    f32x4 o[8] = {};
    float m_i[4], l_i[4];
    #pragma unroll
    for (int r = 0; r < 4; r++) { m_i[r] = -__builtin_inff(); l_i[r] = 0.f; }

    const float SCL   = 0.08838834764831845f * 1.4426950408889634f;
    const float MASKV = -1.0e6f * SCL;

    bf16* Pw = (bf16*)(Buf + w * 2112);   // 16 x 72 bf16, wave-private

    const int kbeg = w * 512;
    for (int k0 = kbeg; k0 < kbeg + 512; k0 += 64) {
        unsigned long long mw[4];
        #pragma unroll
        for (int r = 0; r < 4; r++) {
            const int qr = q0 + q16 * 4 + r;
            mw[r] = mbq[qr * 32 + (k0 >> 6)];
        }

        f32x4 sf[4] = {};
        #pragma unroll
        for (int nf = 0; nf < 4; nf++) {
            bf16x8 kf[4];
            #pragma unroll
            for (int c = 0; c < 4; c++)
                kf[c] = *(const bf16x8*)(
                    Kb + (size_t)(k0 + nf * 16 + l15) * HD + c * 32 + q16 * 8);
            #pragma unroll
            for (int c = 0; c < 4; c++)
                sf[nf] = __builtin_amdgcn_mfma_f32_16x16x32_bf16(
                    qf[c], kf[c], sf[nf], 0, 0, 0);
        }

        #pragma unroll
        for (int nf = 0; nf < 4; nf++)
            #pragma unroll
            for (int r = 0; r < 4; r++) {
                const int mk = (int)((mw[r] >> (nf * 16 + l15)) & 1ull);
                sf[nf][r] = mk ? MASKV : sf[nf][r] * SCL;
            }

        float alpha[4];
        #pragma unroll
        for (int r = 0; r < 4; r++) {
            float mx = fmaxf(fmaxf(sf[0][r], sf[1][r]),
                             fmaxf(sf[2][r], sf[3][r]));
            #pragma unroll
            for (int off = 1; off < 16; off <<= 1)
                mx = fmaxf(mx, __shfl_xor(mx, off, 16));
            const float mnew = fmaxf(m_i[r], mx);
            alpha[r] = __builtin_amdgcn_exp2f(m_i[r] - mnew);
            m_i[r] = mnew;
            float ps = 0.f;
            #pragma unroll
            for (int nf = 0; nf < 4; nf++) {
                const float p = __builtin_amdgcn_exp2f(sf[nf][r] - mnew);
                sf[nf][r] = p;
                ps += p;
            }
            l_i[r] = l_i[r] * alpha[r] + ps;
        }

        #pragma unroll
        for (int df = 0; df < 8; df++)
            #pragma unroll
            for (int r = 0; r < 4; r++)
                o[df][r] *= alpha[r];

        #pragma unroll
        for (int nf = 0; nf < 4; nf++)
            #pragma unroll
            for (int r = 0; r < 4; r++)
                Pw[(q16 * 4 + r) * 72 + nf * 16 + l15] = (bf16)sf[nf][r];

        bf16x8 pf[2];
        #pragma unroll
        for (int cc = 0; cc < 2; cc++)
            pf[cc] = *(const bf16x8*)(Pw + l15 * 72 + cc * 32 + q16 * 8);

        #pragma unroll
        for (int cc = 0; cc < 2; cc++) {
            #pragma unroll
            for (int g = 0; g < 2; g++) {
                bf16x8 vf[4];
                #pragma unroll
                for (int j = 0; j < 4; j++)
                    vf[j] = *(const bf16x8*)(
                        Vb + (size_t)((g * 4 + j) * 16 + l15) * SEQ +
                        k0 + cc * 32 + q16 * 8);
                #pragma unroll
                for (int j = 0; j < 4; j++)
                    o[g * 4 + j] = __builtin_amdgcn_mfma_f32_16x16x32_bf16(
                        pf[cc], vf[j], o[g * 4 + j], 0, 0, 0);
            }
        }
    }

    // THE FIX: reduce l_i across the quad's 16 lanes (full row sum per wave).
    #pragma unroll
    for (int r = 0; r < 4; r++) {
        float ls = l_i[r];
        #pragma unroll
        for (int off = 1; off < 16; off <<= 1)
            ls += __shfl_xor(ls, off, 16);
        l_i[r] = ls;
    }

    // Fence between bf16 P traffic and float publish (overlay guard).
    __syncthreads();

    #pragma unroll
    for (int df = 0; df < 8; df++)
        #pragma unroll
        for (int r = 0; r < 4; r++)
            Buf[w * 2112 + (q16 * 4 + r) * 132 + df * 16 + l15] = o[df][r];
    if (l15 == 0) {
        #pragma unroll
        for (int r = 0; r < 4; r++) {
            Mm[w][q16 * 4 + r] = m_i[r];
            Ll[w][q16 * 4 + r] = l_i[r];
        }
    }
    __syncthreads();

    const int d  = tid & 127;
    const int rg = tid >> 7;
    #pragma unroll
    for (int i = 0; i < 8; i++) {
        const int row = rg * 8 + i;
        const float m0v = Mm[0][row], m1v = Mm[1][row],
                    m2v = Mm[2][row], m3v = Mm[3][row];
        const float M = fmaxf(fmaxf(m0v, m1v), fmaxf(m2v, m3v));
        const float s0 = __builtin_amdgcn_exp2f(m0v - M);
        const float s1 = __builtin_amdgcn_exp2f(m1v - M);
        const float s2 = __builtin_amdgcn_exp2f(m2v - M);
        const float s3 = __builtin_amdgcn_exp2f(m3v - M);
        const float l = Ll[0][row] * s0 + Ll[1][row] * s1 +
                        Ll[2][row] * s2 + Ll[3][row] * s3;
        const float ov = Buf[0 * 2112 + row * 132 + d] * s0 +
                         Buf[1 * 2112 + row * 132 + d] * s1 +
                         Buf[2 * 2112 + row * 132 + d] * s2 +
                         Buf[3 * 2112 + row * 132 + d] * s3;
        out[((size_t)b * SEQ + q0 + row) * DM + h * HD + d] = ov / l;
    }
}

extern "C" void kernel_launch(void* const* d_in, const int* in_sizes, int n_in,
                              void* d_out, int out_size, void* d_ws, size_t ws_size,
                              hipStream_t stream) {
    const float* q    = (const float*)d_in[0];
    const float* k    = (const float*)d_in[1];
    const float* v    = (const float*)d_in[2];
    const void*  mask = d_in[3];
    const float* Wq   = (const float*)d_in[4];
    const float* bq   = (const float*)d_in[5];
    const float* Wk   = (const float*)d_in[6];
    const float* bk   = (const float*)d_in[7];
    const float* Wv   = (const float*)d_in[8];
    const float* bv   = (const float*)d_in[9];
    float* out = (float*)d_out;

    char* ws = (char*)d_ws;
    unsigned long long* bits = (unsigned long long*)ws;
    const size_t bits_bytes = (size_t)NB * SEQ * SEQ / 8;
    unsigned int* flag = (unsigned int*)(ws + bits_bytes);
    char* p = ws + bits_bytes + 256;
    bf16* Qp  = (bf16*)p;                 p += (size_t)NB * SEQ * DM * 2;
    bf16* Kp  = (bf16*)p;                 p += (size_t)NB * SEQ * DM * 2;
    bf16* Vp  = (bf16*)p;                 p += (size_t)NB * SEQ * DM * 2;
    bf16* Wtq = (bf16*)p;                 p += (size_t)DM * DM * 2;
    bf16* Wtk = (bf16*)p;                 p += (size_t)DM * DM * 2;
    bf16* Wtv = (bf16*)p;

    mask_detect<<<1, 256, 0, stream>>>((const unsigned int*)mask, flag);
    mask_pack<<<(NB * SEQ * SEQ) / 256, 256, 0, stream>>>(mask, flag, bits);

    dim3 tgrid(DM / 64, DM / 64, 3);
    transw_kernel<<<tgrid, 256, 0, stream>>>(Wq, Wk, Wv, Wtq, Wtk, Wtv);

    dim3 pgrid(DM / 128, (NB * SEQ) / 128, 3);
    proj_kernel<<<pgrid, 256, 0, stream>>>(q, k, v, Wtq, Wtk, Wtv,
                                           bq, bk, bv, Qp, Kp, Vp);

    dim3 agrid(SEQ / 16, NH, NB);        // (128, 8, 2), 4-wave split-K blocks
    attn_kernel<<<agrid, 256, 0, stream>>>(Qp, Kp, Vp, bits, out);
}